// Round 13
// baseline (803.887 us; speedup 1.0000x reference)
//
#include <hip/hip_runtime.h>

#define LBUF 131072
#define TF   130048
#define TB   64

typedef short bf16x8 __attribute__((ext_vector_type(8)));
typedef float f32x4  __attribute__((ext_vector_type(4)));

__device__ __forceinline__ float ftanh(float x) {
  float ax = fminf(fabsf(x), 15.0f);
  float t  = __expf(2.0f * ax);
  float r  = 1.0f - 2.0f / (t + 1.0f);
  return copysignf(r, x);
}
__device__ __forceinline__ unsigned short b16(float f) {
  unsigned u = __builtin_bit_cast(unsigned, f);
  return (unsigned short)((u + 0x7fffu + ((u >> 16) & 1u)) >> 16);
}
__device__ __forceinline__ float bf2f(unsigned short h) {
  return __builtin_bit_cast(float, ((unsigned)h) << 16);
}

// Pre-pack all weights into split hi/lo bf16 planes (once per call).
__global__ __launch_bounds__(256) void k_pack(
    const float* __restrict__ wf, const float* __restrict__ wg,
    const float* __restrict__ wr, const float* __restrict__ wsk,
    const float* __restrict__ w1, const float* __restrict__ w2,
    unsigned short* __restrict__ whp, unsigned short* __restrict__ w2p,
    unsigned short* __restrict__ w1p, unsigned short* __restrict__ w2fp)
{
  int i = blockIdx.x * 256 + threadIdx.x;
  if (i < 81920) {                       // conv weights: 20 x 4096
    int l = i >> 12, r = i & 4095;
    int m = r >> 6, k = r & 63;
    float v = (m < 32) ? wf[l * 2048 + m * 64 + k] : wg[l * 2048 + (m - 32) * 64 + k];
    unsigned short h = b16(v);
    whp[l * 8192 + m * 128 + k]      = h;
    whp[l * 8192 + m * 128 + 64 + k] = b16(v - bf2f(h));
  } else if (i < 112640) {               // 1x1 weights: 20 x 1536
    int t = i - 81920;
    int l = t / 1536, r = t - l * 1536;
    int m = r >> 5, o = r & 31;
    float v = (m < 32) ? wr[l * 1024 + m * 32 + o] : wsk[l * 512 + (m - 32) * 32 + o];
    unsigned short h = b16(v);
    w2p[l * 3072 + m * 64 + o]      = h;
    w2p[l * 3072 + m * 64 + 32 + o] = b16(v - bf2f(h));
  } else if (i < 116736) {               // W1: 4096
    int t = i - 112640;
    int q = t >> 4, k = t & 15;
    float v = w1[q * 16 + k];
    unsigned short h = b16(v);
    w1p[q * 32 + k]      = h;
    w1p[q * 32 + 16 + k] = b16(v - bf2f(h));
  } else {                               // W2: 65536
    int t = i - 116736;
    int q = t >> 8, k = t & 255;
    float v = w2[q * 256 + k];
    unsigned short h = b16(v);
    w2fp[q * 512 + k]       = h;
    w2fp[q * 512 + 256 + k] = b16(v - bf2f(h));
  }
}

// One dilated layer. Conv-W fragments per-lane from packed global (L1-hot, no LDS).
// LDS: xs 16KB + union(gs 8KB, OutS 13KB) = 29KB -> 5 blocks/CU.
__global__ __launch_bounds__(256) void k_layer(
    const float* __restrict__ xin, float* __restrict__ xout,
    float* __restrict__ skip,
    const unsigned short* __restrict__ wsrc,  // packed conv w, [64 m][128]
    const unsigned short* __restrict__ w2p,   // packed 1x1, [48][64]
    const float* __restrict__ rawin, const float* __restrict__ w_init,
    int Tn, int Told, int d, int pad, int off_s, int first, int writex)
{
  __shared__ alignas(16) char xs[16384];   // X [64 col][256B hi|lo], swz ^((col&15)<<4)
  __shared__ alignas(16) char ubuf[13312]; // gs [64 col][128B hi|lo] ^((col&7)<<4); later OutS
  char* gs = ubuf;
  float (*OutS)[68] = (float (*)[68])&ubuf[0];   // 48 x 68 x 4 = 13056 B

  int tid = threadIdx.x;
  int jb  = blockIdx.x * TB;
  int lane = tid & 63, w = tid >> 6;
  int lr = lane & 15, lg = lane >> 4;

  // 1x1 fragments from packed global (L1/L2-hot)
  bf16x8 a2h[3], a2l[3];
#pragma unroll
  for (int mt = 0; mt < 3; ++mt) {
    int m = mt * 16 + lr;
    a2h[mt] = *(const bf16x8*)(w2p + m * 64 + lg * 8);
    a2l[mt] = *(const bf16x8*)(w2p + m * 64 + 32 + lg * 8);
  }

  // X tile staging: lanes = 16 cols x 4 channels -> 64B-coalesced global reads,
  // 2-way (free) LDS bank pattern on the swizzled writes.
  for (int i = tid; i < 2048; i += 256) {
    int col = (i & 15) | ((i >> 9) << 4);  // 0..63
    int c   = (i >> 4) & 31;               // 0..31
    int e0 = jb + col - pad, e1 = e0 + d;
    float v0, v1;
    if (rawin) {
      float s = w_init[c];
      v0 = (e0 >= 0 && e0 < Told) ? s * rawin[e0] : 0.f;
      v1 = (e1 < Told) ? s * rawin[e1] : 0.f;
    } else {
      v0 = (e0 >= 0 && e0 < Told) ? xin[(size_t)c * LBUF + e0] : 0.f;
      v1 = (e1 < Told) ? xin[(size_t)c * LBUF + e1] : 0.f;
    }
    unsigned short h0 = b16(v0), h1 = b16(v1);
    unsigned short l0 = b16(v0 - bf2f(h0)), l1 = b16(v1 - bf2f(h1));
    unsigned sw = (unsigned)(col & 15) << 4;
    *(unsigned*)(xs + ((col * 256 + c * 4) ^ sw))       = (unsigned)h0 | ((unsigned)h1 << 16);
    *(unsigned*)(xs + ((col * 256 + 128 + c * 4) ^ sw)) = (unsigned)l0 | ((unsigned)l1 << 16);
  }
  __syncthreads();

  int col = w * 16 + lr;
  unsigned swx = (unsigned)lr << 4;

  // ---- GEMM1: K=64, 3-term split; A-fragments per-lane from global ----
  f32x4 acc1[4];
#pragma unroll
  for (int mt = 0; mt < 4; ++mt) acc1[mt] = (f32x4){0.f, 0.f, 0.f, 0.f};
#pragma unroll
  for (int ks = 0; ks < 2; ++ks) {
    bf16x8 bh = *(const bf16x8*)(xs + ((col * 256 + ks * 64 + lg * 16) ^ swx));
    bf16x8 bl = *(const bf16x8*)(xs + ((col * 256 + 128 + ks * 64 + lg * 16) ^ swx));
#pragma unroll
    for (int mt = 0; mt < 4; ++mt) {
      const unsigned short* wrow = wsrc + (mt * 16 + lr) * 128 + ks * 32 + lg * 8;
      bf16x8 ah = *(const bf16x8*)(wrow);
      bf16x8 al = *(const bf16x8*)(wrow + 64);
      acc1[mt] = __builtin_amdgcn_mfma_f32_16x16x32_bf16(ah, bh, acc1[mt], 0, 0, 0);
      acc1[mt] = __builtin_amdgcn_mfma_f32_16x16x32_bf16(ah, bl, acc1[mt], 0, 0, 0);
      acc1[mt] = __builtin_amdgcn_mfma_f32_16x16x32_bf16(al, bh, acc1[mt], 0, 0, 0);
    }
  }

  // ---- gate -> gs (wave-local) ----
  unsigned swg = (unsigned)(col & 7) << 4;
#pragma unroll
  for (int t = 0; t < 2; ++t) {
    float g0 = ftanh(acc1[t][0]) * ftanh(acc1[t + 2][0]);
    float g1 = ftanh(acc1[t][1]) * ftanh(acc1[t + 2][1]);
    float g2 = ftanh(acc1[t][2]) * ftanh(acc1[t + 2][2]);
    float g3 = ftanh(acc1[t][3]) * ftanh(acc1[t + 2][3]);
    unsigned short h0 = b16(g0), h1 = b16(g1), h2 = b16(g2), h3 = b16(g3);
    unsigned short l0 = b16(g0 - bf2f(h0)), l1 = b16(g1 - bf2f(h1));
    unsigned short l2 = b16(g2 - bf2f(h2)), l3 = b16(g3 - bf2f(h3));
    int ob = (t * 16 + lg * 4) * 2;
    *(unsigned*)(gs + ((col * 128 + ob) ^ swg))          = (unsigned)h0 | ((unsigned)h1 << 16);
    *(unsigned*)(gs + ((col * 128 + ob + 4) ^ swg))      = (unsigned)h2 | ((unsigned)h3 << 16);
    *(unsigned*)(gs + ((col * 128 + 64 + ob) ^ swg))     = (unsigned)l0 | ((unsigned)l1 << 16);
    *(unsigned*)(gs + ((col * 128 + 64 + ob + 4) ^ swg)) = (unsigned)l2 | ((unsigned)l3 << 16);
  }

  // ---- GEMM2: K=32, 3-term, A regs; wave-local B ----
  f32x4 acc2[3];
  {
    bf16x8 bgh = *(const bf16x8*)(gs + ((col * 128 + lg * 16) ^ swg));
    bf16x8 bgl = *(const bf16x8*)(gs + ((col * 128 + 64 + lg * 16) ^ swg));
#pragma unroll
    for (int mt = 0; mt < 3; ++mt) {
      f32x4 z = {0.f, 0.f, 0.f, 0.f};
      z = __builtin_amdgcn_mfma_f32_16x16x32_bf16(a2h[mt], bgh, z, 0, 0, 0);
      z = __builtin_amdgcn_mfma_f32_16x16x32_bf16(a2h[mt], bgl, z, 0, 0, 0);
      acc2[mt] = __builtin_amdgcn_mfma_f32_16x16x32_bf16(a2l[mt], bgh, z, 0, 0, 0);
    }
  }

  __syncthreads();   // gs reads done -> reuse ubuf as OutS (xs stays intact)
  {
#pragma unroll
    for (int mt = 0; mt < 2; ++mt)
#pragma unroll
      for (int i = 0; i < 4; ++i) {
        int m = mt * 16 + lg * 4 + i;
        unsigned short xh = *(unsigned short*)(xs + ((col * 256 + (2 * m + 1) * 2) ^ swx));
        unsigned short xl = *(unsigned short*)(xs + ((col * 256 + 128 + (2 * m + 1) * 2) ^ swx));
        OutS[m][col] = acc2[mt][i] + (bf2f(xh) + bf2f(xl));
      }
#pragma unroll
    for (int i = 0; i < 4; ++i)
      OutS[32 + lg * 4 + i][col] = acc2[2][i];
  }
  __syncthreads();

  bool fullN = (jb + TB <= Tn);
  if (writex) {
    if (fullN) {
      int r = tid >> 3, cb = (tid & 7) * 8;
      size_t base = (size_t)r * LBUF + jb + cb;
      float4 v0 = *(float4*)&OutS[r][cb];
      float4 v1 = *(float4*)&OutS[r][cb + 4];
      *(float4*)&xout[base]     = v0;
      *(float4*)&xout[base + 4] = v1;
    } else {
      int c = tid & 63, r0 = tid >> 6;
      int j = jb + c;
      if (j < Tn)
#pragma unroll
        for (int rr = r0; rr < 32; rr += 4)
          xout[(size_t)rr * LBUF + j] = OutS[rr][c];
    }
  }
  if (fullN && ((off_s & 3) == 0) && jb >= off_s) {
    int r = tid >> 4, cb = (tid & 15) * 4;
    size_t base = (size_t)r * TF + (jb - off_s) + cb;
    float4 v = *(float4*)&OutS[32 + r][cb];
    if (first) {
      *(float4*)&skip[base] = v;
    } else {
      float4 o = *(const float4*)&skip[base];
      o.x += v.x; o.y += v.y; o.z += v.z; o.w += v.w;
      *(float4*)&skip[base] = o;
    }
  } else {
    int c = tid & 63, r0 = tid >> 6;
    int j = jb + c, js = j - off_s;
    if (j < Tn && js >= 0) {
#pragma unroll
      for (int rr = r0; rr < 16; rr += 4) {
        if (first) skip[(size_t)rr * TF + js]  = OutS[32 + rr][c];
        else       skip[(size_t)rr * TF + js] += OutS[32 + rr][c];
      }
    }
  }
}

// Fused final MLP. LDS 49KB -> 3 blocks/CU: W2 staged as 16KB hi/lo half-passes,
// sks/w2s/OutS-quarter share one union region; epilogue in 4 quarter-q passes.
__global__ __launch_bounds__(256) void k_final(
    const float* __restrict__ skip,
    const unsigned short* __restrict__ w1p,   // [256][32]
    const unsigned short* __restrict__ w2fp,  // [256][512] (hi 0..255 | lo 256..511)
    float* __restrict__ out)
{
  __shared__ alignas(16) char smem[50176];
  char* h1s = smem;             // [64 col][512B hi] ^((col&31)<<4)   32KB
  char* U   = smem + 32768;     // union: sks 8KB | w2s 16KB | OutSq 17.4KB
  char* sks = U;                // [64 col][128B hi|lo] ^((col&7)<<4)
  char* w2s = U;                // [256 q][64B] ^((q&12)<<2)
  float (*OutSq)[68] = (float (*)[68])U;   // 64 x 68 x 4 = 17408

  int tid = threadIdx.x;
  int jb  = blockIdx.x * 64;
  int lane = tid & 63, w = tid >> 6;
  int lr = lane & 15, lg = lane >> 4;
  int col = w * 16 + lr;

  for (int i = tid; i < 1024; i += 256) {
    int c = i & 63, k2 = i >> 6;
    float v0 = (2 * k2 < 16)     ? fmaxf(skip[(size_t)(2 * k2) * TF + jb + c], 0.f) : 0.f;
    float v1 = (2 * k2 + 1 < 16) ? fmaxf(skip[(size_t)(2 * k2 + 1) * TF + jb + c], 0.f) : 0.f;
    unsigned short h0 = b16(v0), h1 = b16(v1);
    unsigned short l0 = b16(v0 - bf2f(h0)), l1 = b16(v1 - bf2f(h1));
    unsigned sw = (unsigned)(c & 7) << 4;
    *(unsigned*)(sks + ((c * 128 + k2 * 4) ^ sw))      = (unsigned)h0 | ((unsigned)h1 << 16);
    *(unsigned*)(sks + ((c * 128 + 64 + k2 * 4) ^ sw)) = (unsigned)l0 | ((unsigned)l1 << 16);
  }
  __syncthreads();

  unsigned swk = (unsigned)(col & 7) << 4;
  unsigned swh = (unsigned)(col & 31) << 4;

  // GEMM1 -> H1 (wave-local handoff)
  {
    bf16x8 bh = *(const bf16x8*)(sks + ((col * 128 + lg * 16) ^ swk));
    bf16x8 bl = *(const bf16x8*)(sks + ((col * 128 + 64 + lg * 16) ^ swk));
#pragma unroll
    for (int mt = 0; mt < 16; ++mt) {
      bf16x8 ah = {0, 0, 0, 0, 0, 0, 0, 0};
      bf16x8 al = {0, 0, 0, 0, 0, 0, 0, 0};
      if (lg < 2) {
        int m = mt * 16 + lr;
        ah = *(const bf16x8*)(w1p + m * 32 + lg * 8);
        al = *(const bf16x8*)(w1p + m * 32 + 16 + lg * 8);
      }
      f32x4 z = {0.f, 0.f, 0.f, 0.f};
      z = __builtin_amdgcn_mfma_f32_16x16x32_bf16(ah, bh, z, 0, 0, 0);
      z = __builtin_amdgcn_mfma_f32_16x16x32_bf16(ah, bl, z, 0, 0, 0);
      z = __builtin_amdgcn_mfma_f32_16x16x32_bf16(al, bh, z, 0, 0, 0);
      int qb = (mt * 16 + lg * 4) * 2;
      unsigned p01 = (unsigned)b16(fmaxf(z[0], 0.f)) | ((unsigned)b16(fmaxf(z[1], 0.f)) << 16);
      unsigned p23 = (unsigned)b16(fmaxf(z[2], 0.f)) | ((unsigned)b16(fmaxf(z[3], 0.f)) << 16);
      *(unsigned*)(h1s + ((col * 512 + qb) ^ swh))     = p01;
      *(unsigned*)(h1s + ((col * 512 + qb + 4) ^ swh)) = p23;
    }
  }

  // GEMM2: 16 passes (8 k-chunks x {hi,lo}); w2s = 16KB per pass
  f32x4 acco[16];
#pragma unroll
  for (int mt = 0; mt < 16; ++mt) acco[mt] = (f32x4){0.f, 0.f, 0.f, 0.f};

  for (int pass = 0; pass < 16; ++pass) {
    int kb = pass >> 1;
    int lof = (pass & 1) ? 256 : 0;
    __syncthreads();   // pass 0: all GEMM1 sks reads done; else: prev w2s reads done
    for (int i = tid; i < 1024; i += 256) {
      int q = i >> 2, part = i & 3;
      uint4 v = *(const uint4*)(w2fp + q * 512 + lof + kb * 32 + part * 8);
      *(uint4*)(w2s + ((q * 64 + part * 16) ^ ((q & 12) << 2))) = v;
    }
    __syncthreads();
    bf16x8 bh = *(const bf16x8*)(h1s + ((col * 512 + kb * 64 + lg * 16) ^ swh));
#pragma unroll
    for (int mt = 0; mt < 16; ++mt) {
      int row = mt * 16 + lr;
      bf16x8 a = *(const bf16x8*)(w2s + ((row * 64 + lg * 16) ^ ((row & 12) << 2)));
      acco[mt] = __builtin_amdgcn_mfma_f32_16x16x32_bf16(a, bh, acco[mt], 0, 0, 0);
    }
  }

  // epilogue: 4 quarter-q passes through OutSq (p fully unrolled -> acco static)
#pragma unroll
  for (int p = 0; p < 4; ++p) {
    __syncthreads();   // prev quarter reads (or last w2s reads) done
#pragma unroll
    for (int mq = 0; mq < 4; ++mq)
#pragma unroll
      for (int i = 0; i < 4; ++i)
        OutSq[mq * 16 + lg * 4 + i][col] = acco[p * 4 + mq][i];
    __syncthreads();
    int r = tid >> 2, cb = (tid & 3) * 16;
    size_t base = (size_t)(p * 64 + r) * TF + jb + cb;
#pragma unroll
    for (int v = 0; v < 4; ++v)
      *(float4*)&out[base + v * 4] = *(float4*)&OutSq[r][cb + v * 4];
  }
}

extern "C" void kernel_launch(void* const* d_in, const int* in_sizes, int n_in,
                              void* d_out, int out_size, void* d_ws, size_t ws_size,
                              hipStream_t stream) {
  const float* x_in     = (const float*)d_in[0];
  const float* w_init   = (const float*)d_in[1];
  const float* w_filter = (const float*)d_in[2];
  const float* w_gate   = (const float*)d_in[3];
  const float* w_res    = (const float*)d_in[4];
  const float* w_skip   = (const float*)d_in[5];
  const float* w_f1     = (const float*)d_in[6];
  const float* w_f2     = (const float*)d_in[7];
  float* out = (float*)d_out;

  float* xa    = (float*)d_ws;
  float* xb    = xa + 32 * (size_t)LBUF;
  float* skipb = xb + 32 * (size_t)LBUF;
  unsigned short* whp  = (unsigned short*)(skipb + 16 * (size_t)TF);
  unsigned short* w2p  = whp + 20 * 8192;
  unsigned short* w1p  = w2p + 20 * 3072;
  unsigned short* w2fp = w1p + 8192;

  k_pack<<<712, 256, 0, stream>>>(w_filter, w_gate, w_res, w_skip, w_f1, w_f2,
                                  whp, w2p, w1p, w2fp);

  int T = LBUF;
  for (int idx = 0; idx < 20; ++idx) {
    int d    = 1 << (idx % 10);
    int pad  = (d - (T % d)) % d;
    int Tn   = T + pad - d;
    int offs = Tn - TF;
    k_layer<<<(Tn + TB - 1) / TB, 256, 0, stream>>>(
        xa, xb, skipb,
        whp + (size_t)idx * 8192, w2p + (size_t)idx * 3072,
        (idx == 0) ? x_in : nullptr, w_init,
        Tn, T, d, pad, offs, (idx == 0) ? 1 : 0, (idx == 19) ? 0 : 1);
    float* t = xa; xa = xb; xb = t;
    T = Tn;
  }

  k_final<<<TF / 64, 256, 0, stream>>>(skipb, w1p, w2fp, out);
}

// Round 14
// 714.723 us; speedup vs baseline: 1.1248x; 1.1248x over previous
//
#include <hip/hip_runtime.h>
#include <hip/hip_bf16.h>

#define LBUF 131072
#define TF   130048
#define TB   64

typedef short bf16x8 __attribute__((ext_vector_type(8)));
typedef float f32x4  __attribute__((ext_vector_type(4)));

__device__ __forceinline__ float ftanh(float x) {
  float ax = fminf(fabsf(x), 15.0f);
  float t  = __expf(2.0f * ax);
  float r  = 1.0f - 2.0f / (t + 1.0f);
  return copysignf(r, x);
}
// fp32 -> bf16 RNE via native convert (compiler emits v_cvt / fuses v_cvt_pk_bf16_f32)
__device__ __forceinline__ unsigned short b16(float f) {
  return __builtin_bit_cast(unsigned short, __float2bfloat16(f));
}
__device__ __forceinline__ float bf2f(unsigned short h) {
  return __builtin_bit_cast(float, ((unsigned)h) << 16);
}

// Pre-pack all weights into split hi/lo bf16 planes (once per call).
__global__ __launch_bounds__(256) void k_pack(
    const float* __restrict__ wf, const float* __restrict__ wg,
    const float* __restrict__ wr, const float* __restrict__ wsk,
    const float* __restrict__ w1, const float* __restrict__ w2,
    unsigned short* __restrict__ whp, unsigned short* __restrict__ w2p,
    unsigned short* __restrict__ w1p, unsigned short* __restrict__ w2fp)
{
  int i = blockIdx.x * 256 + threadIdx.x;
  if (i < 81920) {                       // conv weights: 20 x 4096
    int l = i >> 12, r = i & 4095;
    int m = r >> 6, k = r & 63;
    float v = (m < 32) ? wf[l * 2048 + m * 64 + k] : wg[l * 2048 + (m - 32) * 64 + k];
    unsigned short h = b16(v);
    whp[l * 8192 + m * 128 + k]      = h;
    whp[l * 8192 + m * 128 + 64 + k] = b16(v - bf2f(h));
  } else if (i < 112640) {               // 1x1 weights: 20 x 1536
    int t = i - 81920;
    int l = t / 1536, r = t - l * 1536;
    int m = r >> 5, o = r & 31;
    float v = (m < 32) ? wr[l * 1024 + m * 32 + o] : wsk[l * 512 + (m - 32) * 32 + o];
    unsigned short h = b16(v);
    w2p[l * 3072 + m * 64 + o]      = h;
    w2p[l * 3072 + m * 64 + 32 + o] = b16(v - bf2f(h));
  } else if (i < 116736) {               // W1: 4096
    int t = i - 112640;
    int q = t >> 4, k = t & 15;
    float v = w1[q * 16 + k];
    unsigned short h = b16(v);
    w1p[q * 32 + k]      = h;
    w1p[q * 32 + 16 + k] = b16(v - bf2f(h));
  } else {                               // W2: 65536
    int t = i - 116736;
    int q = t >> 8, k = t & 255;
    float v = w2[q * 256 + k];
    unsigned short h = b16(v);
    w2fp[q * 512 + k]       = h;
    w2fp[q * 512 + 256 + k] = b16(v - bf2f(h));
  }
}

// One dilated layer: split-bf16 MFMA, swizzled LDS, TB=64 (round-12 structure).
// Layer 0: rawin != null -> X staged as w_init[c]*rawin[e] (init conv folded in).
__global__ __launch_bounds__(256) void k_layer(
    const float* __restrict__ xin, float* __restrict__ xout,
    float* __restrict__ skip,
    const unsigned* __restrict__ wsrc,        // packed conv w, 4096 u32
    const unsigned short* __restrict__ w2p,   // packed 1x1, [48][64]
    const float* __restrict__ rawin, const float* __restrict__ w_init,
    int Tn, int Told, int d, int pad, int off_s, int first, int writex)
{
  __shared__ alignas(16) char xs[16384];   // X [64 col][256B: hi|lo], swz ^((col&15)<<4)
  __shared__ alignas(16) char gs[8192];    // G [64 col][128B: hi|lo], swz ^((col&7)<<4)
  __shared__ alignas(16) char wbuf[16384]; // W [64 m][256B: hi|lo], swz ^((m&15)<<4); later OutS
  float (*OutS)[68] = (float (*)[68])&wbuf[0];   // 48 x 68 x 4 = 13056 B

  int tid = threadIdx.x;
  int jb  = blockIdx.x * TB;
  int lane = tid & 63, w = tid >> 6;
  int lr = lane & 15, lg = lane >> 4;

  // 1x1 fragments from packed global (L1/L2-hot)
  bf16x8 a2h[3], a2l[3];
#pragma unroll
  for (int mt = 0; mt < 3; ++mt) {
    int m = mt * 16 + lr;
    a2h[mt] = *(const bf16x8*)(w2p + m * 64 + lg * 8);
    a2l[mt] = *(const bf16x8*)(w2p + m * 64 + 32 + lg * 8);
  }

  // conv weights: pure u32 copies into swizzled LDS
  for (int i = tid; i < 4096; i += 256) {
    int m = i >> 6, j = i & 63;
    *(unsigned*)(wbuf + ((m * 256 + j * 4) ^ ((m & 15) << 4))) = wsrc[i];
  }
  // X tile: fp32 -> split bf16 (layer 0: on-the-fly init conv)
  for (int i = tid; i < 2048; i += 256) {
    int col = i & 63, c = i >> 6;
    int e0 = jb + col - pad, e1 = e0 + d;
    float v0, v1;
    if (rawin) {
      float s = w_init[c];
      v0 = (e0 >= 0 && e0 < Told) ? s * rawin[e0] : 0.f;
      v1 = (e1 < Told) ? s * rawin[e1] : 0.f;
    } else {
      v0 = (e0 >= 0 && e0 < Told) ? xin[(size_t)c * LBUF + e0] : 0.f;
      v1 = (e1 < Told) ? xin[(size_t)c * LBUF + e1] : 0.f;
    }
    unsigned short h0 = b16(v0), h1 = b16(v1);
    unsigned short l0 = b16(v0 - bf2f(h0)), l1 = b16(v1 - bf2f(h1));
    unsigned sw = (unsigned)(col & 15) << 4;
    *(unsigned*)(xs + ((col * 256 + c * 4) ^ sw))       = (unsigned)h0 | ((unsigned)h1 << 16);
    *(unsigned*)(xs + ((col * 256 + 128 + c * 4) ^ sw)) = (unsigned)l0 | ((unsigned)l1 << 16);
  }
  __syncthreads();

  int col = w * 16 + lr;
  unsigned swx = (unsigned)lr << 4;

  // ---- GEMM1: K=64, 3-term split ----
  f32x4 acc1[4];
#pragma unroll
  for (int mt = 0; mt < 4; ++mt) acc1[mt] = (f32x4){0.f, 0.f, 0.f, 0.f};
#pragma unroll
  for (int ks = 0; ks < 2; ++ks) {
    bf16x8 bh = *(const bf16x8*)(xs + ((col * 256 + ks * 64 + lg * 16) ^ swx));
    bf16x8 bl = *(const bf16x8*)(xs + ((col * 256 + 128 + ks * 64 + lg * 16) ^ swx));
#pragma unroll
    for (int mt = 0; mt < 4; ++mt) {
      int row = mt * 16 + lr;
      bf16x8 ah = *(const bf16x8*)(wbuf + ((row * 256 + ks * 64 + lg * 16) ^ swx));
      bf16x8 al = *(const bf16x8*)(wbuf + ((row * 256 + 128 + ks * 64 + lg * 16) ^ swx));
      acc1[mt] = __builtin_amdgcn_mfma_f32_16x16x32_bf16(ah, bh, acc1[mt], 0, 0, 0);
      acc1[mt] = __builtin_amdgcn_mfma_f32_16x16x32_bf16(ah, bl, acc1[mt], 0, 0, 0);
      acc1[mt] = __builtin_amdgcn_mfma_f32_16x16x32_bf16(al, bh, acc1[mt], 0, 0, 0);
    }
  }

  // ---- gate -> gs (wave-local) ----
  unsigned swg = (unsigned)(col & 7) << 4;
#pragma unroll
  for (int t = 0; t < 2; ++t) {
    float g0 = ftanh(acc1[t][0]) * ftanh(acc1[t + 2][0]);
    float g1 = ftanh(acc1[t][1]) * ftanh(acc1[t + 2][1]);
    float g2 = ftanh(acc1[t][2]) * ftanh(acc1[t + 2][2]);
    float g3 = ftanh(acc1[t][3]) * ftanh(acc1[t + 2][3]);
    unsigned short h0 = b16(g0), h1 = b16(g1), h2 = b16(g2), h3 = b16(g3);
    unsigned short l0 = b16(g0 - bf2f(h0)), l1 = b16(g1 - bf2f(h1));
    unsigned short l2 = b16(g2 - bf2f(h2)), l3 = b16(g3 - bf2f(h3));
    int ob = (t * 16 + lg * 4) * 2;
    *(unsigned*)(gs + ((col * 128 + ob) ^ swg))          = (unsigned)h0 | ((unsigned)h1 << 16);
    *(unsigned*)(gs + ((col * 128 + ob + 4) ^ swg))      = (unsigned)h2 | ((unsigned)h3 << 16);
    *(unsigned*)(gs + ((col * 128 + 64 + ob) ^ swg))     = (unsigned)l0 | ((unsigned)l1 << 16);
    *(unsigned*)(gs + ((col * 128 + 64 + ob + 4) ^ swg)) = (unsigned)l2 | ((unsigned)l3 << 16);
  }

  // ---- GEMM2: K=32, 3-term, A regs; wave-local B ----
  f32x4 acc2[3];
  {
    bf16x8 bgh = *(const bf16x8*)(gs + ((col * 128 + lg * 16) ^ swg));
    bf16x8 bgl = *(const bf16x8*)(gs + ((col * 128 + 64 + lg * 16) ^ swg));
#pragma unroll
    for (int mt = 0; mt < 3; ++mt) {
      f32x4 z = {0.f, 0.f, 0.f, 0.f};
      z = __builtin_amdgcn_mfma_f32_16x16x32_bf16(a2h[mt], bgh, z, 0, 0, 0);
      z = __builtin_amdgcn_mfma_f32_16x16x32_bf16(a2h[mt], bgl, z, 0, 0, 0);
      acc2[mt] = __builtin_amdgcn_mfma_f32_16x16x32_bf16(a2l[mt], bgh, z, 0, 0, 0);
    }
  }

  __syncthreads();   // Ws reads done -> reuse wbuf as OutS
  {
#pragma unroll
    for (int mt = 0; mt < 2; ++mt)
#pragma unroll
      for (int i = 0; i < 4; ++i) {
        int m = mt * 16 + lg * 4 + i;
        unsigned short xh = *(unsigned short*)(xs + ((col * 256 + (2 * m + 1) * 2) ^ swx));
        unsigned short xl = *(unsigned short*)(xs + ((col * 256 + 128 + (2 * m + 1) * 2) ^ swx));
        OutS[m][col] = acc2[mt][i] + (bf2f(xh) + bf2f(xl));
      }
#pragma unroll
    for (int i = 0; i < 4; ++i)
      OutS[32 + lg * 4 + i][col] = acc2[2][i];
  }
  __syncthreads();

  bool fullN = (jb + TB <= Tn);
  if (writex) {
    if (fullN) {
      int r = tid >> 3, cb = (tid & 7) * 8;
      size_t base = (size_t)r * LBUF + jb + cb;
      float4 v0 = *(float4*)&OutS[r][cb];
      float4 v1 = *(float4*)&OutS[r][cb + 4];
      *(float4*)&xout[base]     = v0;
      *(float4*)&xout[base + 4] = v1;
    } else {
      int c = tid & 63, r0 = tid >> 6;
      int j = jb + c;
      if (j < Tn)
#pragma unroll
        for (int rr = r0; rr < 32; rr += 4)
          xout[(size_t)rr * LBUF + j] = OutS[rr][c];
    }
  }
  if (fullN && ((off_s & 3) == 0) && jb >= off_s) {
    int r = tid >> 4, cb = (tid & 15) * 4;
    size_t base = (size_t)r * TF + (jb - off_s) + cb;
    float4 v = *(float4*)&OutS[32 + r][cb];
    if (first) {
      *(float4*)&skip[base] = v;
    } else {
      float4 o = *(const float4*)&skip[base];
      o.x += v.x; o.y += v.y; o.z += v.z; o.w += v.w;
      *(float4*)&skip[base] = o;
    }
  } else {
    int c = tid & 63, r0 = tid >> 6;
    int j = jb + c, js = j - off_s;
    if (j < Tn && js >= 0) {
#pragma unroll
      for (int rr = r0; rr < 16; rr += 4) {
        if (first) skip[(size_t)rr * TF + js]  = OutS[32 + rr][c];
        else       skip[(size_t)rr * TF + js] += OutS[32 + rr][c];
      }
    }
  }
}

// Fused final MLP (round-12 structure + T14 register prefetch of W2 chunks).
__global__ __launch_bounds__(256) void k_final(
    const float* __restrict__ skip,
    const unsigned short* __restrict__ w1p,   // [256][32]
    const unsigned short* __restrict__ w2fp,  // [256][512] (hi 0..255 | lo 256..511)
    float* __restrict__ out)
{
  __shared__ alignas(16) char smem[73728];
  char* sks = smem;             // [64 col][128B hi|lo] ^((col&7)<<4)   8KB
  char* h1s = smem + 8192;      // [64 col][512B hi]    ^((col&31)<<4) 32KB
  char* w2s = smem + 40960;     // [256 q][128B hi|lo]  ^((q&7)<<4)   32KB
  float (*OutS)[68] = (float (*)[68])&smem[0];   // 256*68*4 = 69632

  int tid = threadIdx.x;
  int jb  = blockIdx.x * 64;
  int lane = tid & 63, w = tid >> 6;
  int lr = lane & 15, lg = lane >> 4;
  int col = w * 16 + lr;

  for (int i = tid; i < 1024; i += 256) {
    int c = i & 63, k2 = i >> 6;
    float v0 = (2 * k2 < 16)     ? fmaxf(skip[(size_t)(2 * k2) * TF + jb + c], 0.f) : 0.f;
    float v1 = (2 * k2 + 1 < 16) ? fmaxf(skip[(size_t)(2 * k2 + 1) * TF + jb + c], 0.f) : 0.f;
    unsigned short h0 = b16(v0), h1 = b16(v1);
    unsigned short l0 = b16(v0 - bf2f(h0)), l1 = b16(v1 - bf2f(h1));
    unsigned sw = (unsigned)(c & 7) << 4;
    *(unsigned*)(sks + ((c * 128 + k2 * 4) ^ sw))      = (unsigned)h0 | ((unsigned)h1 << 16);
    *(unsigned*)(sks + ((c * 128 + 64 + k2 * 4) ^ sw)) = (unsigned)l0 | ((unsigned)l1 << 16);
  }
  __syncthreads();

  unsigned swk = (unsigned)(col & 7) << 4;
  unsigned swh = (unsigned)(col & 31) << 4;

  // GEMM1 -> H1 (wave-local handoff)
  {
    bf16x8 bh = *(const bf16x8*)(sks + ((col * 128 + lg * 16) ^ swk));
    bf16x8 bl = *(const bf16x8*)(sks + ((col * 128 + 64 + lg * 16) ^ swk));
#pragma unroll
    for (int mt = 0; mt < 16; ++mt) {
      bf16x8 ah = {0, 0, 0, 0, 0, 0, 0, 0};
      bf16x8 al = {0, 0, 0, 0, 0, 0, 0, 0};
      if (lg < 2) {
        int m = mt * 16 + lr;
        ah = *(const bf16x8*)(w1p + m * 32 + lg * 8);
        al = *(const bf16x8*)(w1p + m * 32 + 16 + lg * 8);
      }
      f32x4 z = {0.f, 0.f, 0.f, 0.f};
      z = __builtin_amdgcn_mfma_f32_16x16x32_bf16(ah, bh, z, 0, 0, 0);
      z = __builtin_amdgcn_mfma_f32_16x16x32_bf16(ah, bl, z, 0, 0, 0);
      z = __builtin_amdgcn_mfma_f32_16x16x32_bf16(al, bh, z, 0, 0, 0);
      int qb = (mt * 16 + lg * 4) * 2;
      unsigned p01 = (unsigned)b16(fmaxf(z[0], 0.f)) | ((unsigned)b16(fmaxf(z[1], 0.f)) << 16);
      unsigned p23 = (unsigned)b16(fmaxf(z[2], 0.f)) | ((unsigned)b16(fmaxf(z[3], 0.f)) << 16);
      *(unsigned*)(h1s + ((col * 512 + qb) ^ swh))     = p01;
      *(unsigned*)(h1s + ((col * 512 + qb + 4) ^ swh)) = p23;
    }
  }

  // GEMM2: K=256 in 8 chunks; W2 chunk staged via register double-buffer (T14):
  // prefetch chunk kb+1's 8 uint4 into regs BEFORE chunk kb's MFMAs -> latency hidden.
  f32x4 acco[16];
#pragma unroll
  for (int mt = 0; mt < 16; ++mt) acco[mt] = (f32x4){0.f, 0.f, 0.f, 0.f};

  // per-thread staging slots (same LDS dst every chunk)
  int qq[8], dst[8], srcoff[8];
#pragma unroll
  for (int it = 0; it < 8; ++it) {
    int i = tid + it * 256;
    int q = i >> 3, r4 = i & 7;
    qq[it] = q;
    dst[it] = (q * 128 + ((r4 & 3) * 16) + ((r4 >= 4) ? 64 : 0)) ^ ((q & 7) << 4);
    srcoff[it] = q * 512 + ((r4 >= 4) ? 256 : 0) + (r4 & 3) * 8;
  }
  uint4 pf[8];
#pragma unroll
  for (int it = 0; it < 8; ++it) pf[it] = *(const uint4*)(w2fp + srcoff[it]);  // kb=0

  for (int kb = 0; kb < 8; ++kb) {
    __syncthreads();   // prev chunk reads (or GEMM1 sks reads) done
#pragma unroll
    for (int it = 0; it < 8; ++it) *(uint4*)(w2s + dst[it]) = pf[it];
    __syncthreads();
    if (kb < 7) {
#pragma unroll
      for (int it = 0; it < 8; ++it)
        pf[it] = *(const uint4*)(w2fp + srcoff[it] + (kb + 1) * 32);
    }
    bf16x8 bh = *(const bf16x8*)(h1s + ((col * 512 + kb * 64 + lg * 16) ^ swh));
#pragma unroll
    for (int mt = 0; mt < 16; ++mt) {
      int row = mt * 16 + lr;
      unsigned swr = (unsigned)(row & 7) << 4;
      bf16x8 ah = *(const bf16x8*)(w2s + ((row * 128 + lg * 16) ^ swr));
      bf16x8 al = *(const bf16x8*)(w2s + ((row * 128 + 64 + lg * 16) ^ swr));
      acco[mt] = __builtin_amdgcn_mfma_f32_16x16x32_bf16(ah, bh, acco[mt], 0, 0, 0);
      acco[mt] = __builtin_amdgcn_mfma_f32_16x16x32_bf16(al, bh, acco[mt], 0, 0, 0);
    }
  }

  __syncthreads();
#pragma unroll
  for (int mt = 0; mt < 16; ++mt)
#pragma unroll
    for (int i = 0; i < 4; ++i)
      OutS[mt * 16 + lg * 4 + i][col] = acco[mt][i];
  __syncthreads();

  int ty = tid >> 3, tx = tid & 7;
#pragma unroll
  for (int i = 0; i < 8; ++i) {
    int q = ty * 8 + i;
    float4 v0 = *(float4*)&OutS[q][tx * 8];
    float4 v1 = *(float4*)&OutS[q][tx * 8 + 4];
    size_t base = (size_t)q * TF + jb + tx * 8;
    *(float4*)&out[base]     = v0;
    *(float4*)&out[base + 4] = v1;
  }
}

extern "C" void kernel_launch(void* const* d_in, const int* in_sizes, int n_in,
                              void* d_out, int out_size, void* d_ws, size_t ws_size,
                              hipStream_t stream) {
  const float* x_in     = (const float*)d_in[0];
  const float* w_init   = (const float*)d_in[1];
  const float* w_filter = (const float*)d_in[2];
  const float* w_gate   = (const float*)d_in[3];
  const float* w_res    = (const float*)d_in[4];
  const float* w_skip   = (const float*)d_in[5];
  const float* w_f1     = (const float*)d_in[6];
  const float* w_f2     = (const float*)d_in[7];
  float* out = (float*)d_out;

  float* xa    = (float*)d_ws;
  float* xb    = xa + 32 * (size_t)LBUF;
  float* skipb = xb + 32 * (size_t)LBUF;
  unsigned short* whp  = (unsigned short*)(skipb + 16 * (size_t)TF);
  unsigned short* w2p  = whp + 20 * 8192;
  unsigned short* w1p  = w2p + 20 * 3072;
  unsigned short* w2fp = w1p + 8192;

  k_pack<<<712, 256, 0, stream>>>(w_filter, w_gate, w_res, w_skip, w_f1, w_f2,
                                  whp, w2p, w1p, w2fp);

  int T = LBUF;
  for (int idx = 0; idx < 20; ++idx) {
    int d    = 1 << (idx % 10);
    int pad  = (d - (T % d)) % d;
    int Tn   = T + pad - d;
    int offs = Tn - TF;
    k_layer<<<(Tn + TB - 1) / TB, 256, 0, stream>>>(
        xa, xb, skipb,
        (const unsigned*)(whp + (size_t)idx * 8192), w2p + (size_t)idx * 3072,
        (idx == 0) ? x_in : nullptr, w_init,
        Tn, T, d, pad, offs, (idx == 0) ? 1 : 0, (idx == 19) ? 0 : 1);
    float* t = xa; xa = xb; xb = t;
    T = Tn;
  }

  k_final<<<TF / 64, 256, 0, stream>>>(skipb, w1p, w2fp, out);
}

// Round 15
// 604.827 us; speedup vs baseline: 1.3291x; 1.1817x over previous
//
#include <hip/hip_runtime.h>
#include <hip/hip_bf16.h>

#define LBUF 131072
#define TF   130048
#define TB   64

typedef short bf16x8 __attribute__((ext_vector_type(8)));
typedef float f32x4  __attribute__((ext_vector_type(4)));

__device__ __forceinline__ float ftanh(float x) {
  float ax = fminf(fabsf(x), 15.0f);
  float t  = __expf(2.0f * ax);
  float r  = 1.0f - 2.0f / (t + 1.0f);
  return copysignf(r, x);
}
__device__ __forceinline__ unsigned short b16(float f) {
  return __builtin_bit_cast(unsigned short, __float2bfloat16(f));
}
__device__ __forceinline__ float bf2f(unsigned short h) {
  return __builtin_bit_cast(float, ((unsigned)h) << 16);
}

// Pre-pack all weights into split hi/lo bf16 planes (once per call).
__global__ __launch_bounds__(256) void k_pack(
    const float* __restrict__ wf, const float* __restrict__ wg,
    const float* __restrict__ wr, const float* __restrict__ wsk,
    const float* __restrict__ w1, const float* __restrict__ w2,
    unsigned short* __restrict__ whp, unsigned short* __restrict__ w2p,
    unsigned short* __restrict__ w1p, unsigned short* __restrict__ w2fp)
{
  int i = blockIdx.x * 256 + threadIdx.x;
  if (i < 81920) {                       // conv weights: 20 x 4096
    int l = i >> 12, r = i & 4095;
    int m = r >> 6, k = r & 63;
    float v = (m < 32) ? wf[l * 2048 + m * 64 + k] : wg[l * 2048 + (m - 32) * 64 + k];
    unsigned short h = b16(v);
    whp[l * 8192 + m * 128 + k]      = h;
    whp[l * 8192 + m * 128 + 64 + k] = b16(v - bf2f(h));
  } else if (i < 112640) {               // 1x1 weights: 20 x 1536
    int t = i - 81920;
    int l = t / 1536, r = t - l * 1536;
    int m = r >> 5, o = r & 31;
    float v = (m < 32) ? wr[l * 1024 + m * 32 + o] : wsk[l * 512 + (m - 32) * 32 + o];
    unsigned short h = b16(v);
    w2p[l * 3072 + m * 64 + o]      = h;
    w2p[l * 3072 + m * 64 + 32 + o] = b16(v - bf2f(h));
  } else if (i < 116736) {               // W1: 4096
    int t = i - 112640;
    int q = t >> 4, k = t & 15;
    float v = w1[q * 16 + k];
    unsigned short h = b16(v);
    w1p[q * 32 + k]      = h;
    w1p[q * 32 + 16 + k] = b16(v - bf2f(h));
  } else {                               // W2: 65536
    int t = i - 116736;
    int q = t >> 8, k = t & 255;
    float v = w2[q * 256 + k];
    unsigned short h = b16(v);
    w2fp[q * 512 + k]       = h;
    w2fp[q * 512 + 256 + k] = b16(v - bf2f(h));
  }
}

// One dilated layer: split-bf16 MFMA, swizzled LDS, TB=64 (round-12 structure).
// Layer 0: rawin != null -> X staged as w_init[c]*rawin[e] (init conv folded in).
__global__ __launch_bounds__(256) void k_layer(
    const float* __restrict__ xin, float* __restrict__ xout,
    float* __restrict__ skip,
    const unsigned* __restrict__ wsrc,        // packed conv w, 4096 u32
    const unsigned short* __restrict__ w2p,   // packed 1x1, [48][64]
    const float* __restrict__ rawin, const float* __restrict__ w_init,
    int Tn, int Told, int d, int pad, int off_s, int first, int writex)
{
  __shared__ alignas(16) char xs[16384];   // X [64 col][256B: hi|lo], swz ^((col&15)<<4)
  __shared__ alignas(16) char gs[8192];    // G [64 col][128B: hi|lo], swz ^((col&7)<<4)
  __shared__ alignas(16) char wbuf[16384]; // W [64 m][256B: hi|lo], swz ^((m&15)<<4); later OutS
  float (*OutS)[68] = (float (*)[68])&wbuf[0];   // 48 x 68 x 4 = 13056 B

  int tid = threadIdx.x;
  int jb  = blockIdx.x * TB;
  int lane = tid & 63, w = tid >> 6;
  int lr = lane & 15, lg = lane >> 4;

  // 1x1 fragments from packed global (L1/L2-hot)
  bf16x8 a2h[3], a2l[3];
#pragma unroll
  for (int mt = 0; mt < 3; ++mt) {
    int m = mt * 16 + lr;
    a2h[mt] = *(const bf16x8*)(w2p + m * 64 + lg * 8);
    a2l[mt] = *(const bf16x8*)(w2p + m * 64 + 32 + lg * 8);
  }

  // conv weights: pure u32 copies into swizzled LDS
  for (int i = tid; i < 4096; i += 256) {
    int m = i >> 6, j = i & 63;
    *(unsigned*)(wbuf + ((m * 256 + j * 4) ^ ((m & 15) << 4))) = wsrc[i];
  }
  // X tile: fp32 -> split bf16 (layer 0: on-the-fly init conv)
  for (int i = tid; i < 2048; i += 256) {
    int col = i & 63, c = i >> 6;
    int e0 = jb + col - pad, e1 = e0 + d;
    float v0, v1;
    if (rawin) {
      float s = w_init[c];
      v0 = (e0 >= 0 && e0 < Told) ? s * rawin[e0] : 0.f;
      v1 = (e1 < Told) ? s * rawin[e1] : 0.f;
    } else {
      v0 = (e0 >= 0 && e0 < Told) ? xin[(size_t)c * LBUF + e0] : 0.f;
      v1 = (e1 < Told) ? xin[(size_t)c * LBUF + e1] : 0.f;
    }
    unsigned short h0 = b16(v0), h1 = b16(v1);
    unsigned short l0 = b16(v0 - bf2f(h0)), l1 = b16(v1 - bf2f(h1));
    unsigned sw = (unsigned)(col & 15) << 4;
    *(unsigned*)(xs + ((col * 256 + c * 4) ^ sw))       = (unsigned)h0 | ((unsigned)h1 << 16);
    *(unsigned*)(xs + ((col * 256 + 128 + c * 4) ^ sw)) = (unsigned)l0 | ((unsigned)l1 << 16);
  }
  __syncthreads();

  int col = w * 16 + lr;
  unsigned swx = (unsigned)lr << 4;

  // ---- GEMM1: K=64, 3-term split ----
  f32x4 acc1[4];
#pragma unroll
  for (int mt = 0; mt < 4; ++mt) acc1[mt] = (f32x4){0.f, 0.f, 0.f, 0.f};
#pragma unroll
  for (int ks = 0; ks < 2; ++ks) {
    bf16x8 bh = *(const bf16x8*)(xs + ((col * 256 + ks * 64 + lg * 16) ^ swx));
    bf16x8 bl = *(const bf16x8*)(xs + ((col * 256 + 128 + ks * 64 + lg * 16) ^ swx));
#pragma unroll
    for (int mt = 0; mt < 4; ++mt) {
      int row = mt * 16 + lr;
      bf16x8 ah = *(const bf16x8*)(wbuf + ((row * 256 + ks * 64 + lg * 16) ^ swx));
      bf16x8 al = *(const bf16x8*)(wbuf + ((row * 256 + 128 + ks * 64 + lg * 16) ^ swx));
      acc1[mt] = __builtin_amdgcn_mfma_f32_16x16x32_bf16(ah, bh, acc1[mt], 0, 0, 0);
      acc1[mt] = __builtin_amdgcn_mfma_f32_16x16x32_bf16(ah, bl, acc1[mt], 0, 0, 0);
      acc1[mt] = __builtin_amdgcn_mfma_f32_16x16x32_bf16(al, bh, acc1[mt], 0, 0, 0);
    }
  }

  // ---- gate -> gs (wave-local) ----
  unsigned swg = (unsigned)(col & 7) << 4;
#pragma unroll
  for (int t = 0; t < 2; ++t) {
    float g0 = ftanh(acc1[t][0]) * ftanh(acc1[t + 2][0]);
    float g1 = ftanh(acc1[t][1]) * ftanh(acc1[t + 2][1]);
    float g2 = ftanh(acc1[t][2]) * ftanh(acc1[t + 2][2]);
    float g3 = ftanh(acc1[t][3]) * ftanh(acc1[t + 2][3]);
    unsigned short h0 = b16(g0), h1 = b16(g1), h2 = b16(g2), h3 = b16(g3);
    unsigned short l0 = b16(g0 - bf2f(h0)), l1 = b16(g1 - bf2f(h1));
    unsigned short l2 = b16(g2 - bf2f(h2)), l3 = b16(g3 - bf2f(h3));
    int ob = (t * 16 + lg * 4) * 2;
    *(unsigned*)(gs + ((col * 128 + ob) ^ swg))          = (unsigned)h0 | ((unsigned)h1 << 16);
    *(unsigned*)(gs + ((col * 128 + ob + 4) ^ swg))      = (unsigned)h2 | ((unsigned)h3 << 16);
    *(unsigned*)(gs + ((col * 128 + 64 + ob) ^ swg))     = (unsigned)l0 | ((unsigned)l1 << 16);
    *(unsigned*)(gs + ((col * 128 + 64 + ob + 4) ^ swg)) = (unsigned)l2 | ((unsigned)l3 << 16);
  }

  // ---- GEMM2: K=32, 3-term, A regs; wave-local B ----
  f32x4 acc2[3];
  {
    bf16x8 bgh = *(const bf16x8*)(gs + ((col * 128 + lg * 16) ^ swg));
    bf16x8 bgl = *(const bf16x8*)(gs + ((col * 128 + 64 + lg * 16) ^ swg));
#pragma unroll
    for (int mt = 0; mt < 3; ++mt) {
      f32x4 z = {0.f, 0.f, 0.f, 0.f};
      z = __builtin_amdgcn_mfma_f32_16x16x32_bf16(a2h[mt], bgh, z, 0, 0, 0);
      z = __builtin_amdgcn_mfma_f32_16x16x32_bf16(a2h[mt], bgl, z, 0, 0, 0);
      acc2[mt] = __builtin_amdgcn_mfma_f32_16x16x32_bf16(a2l[mt], bgh, z, 0, 0, 0);
    }
  }

  __syncthreads();   // Ws reads done -> reuse wbuf as OutS
  {
#pragma unroll
    for (int mt = 0; mt < 2; ++mt)
#pragma unroll
      for (int i = 0; i < 4; ++i) {
        int m = mt * 16 + lg * 4 + i;
        unsigned short xh = *(unsigned short*)(xs + ((col * 256 + (2 * m + 1) * 2) ^ swx));
        unsigned short xl = *(unsigned short*)(xs + ((col * 256 + 128 + (2 * m + 1) * 2) ^ swx));
        OutS[m][col] = acc2[mt][i] + (bf2f(xh) + bf2f(xl));
      }
#pragma unroll
    for (int i = 0; i < 4; ++i)
      OutS[32 + lg * 4 + i][col] = acc2[2][i];
  }
  __syncthreads();

  bool fullN = (jb + TB <= Tn);
  if (writex) {
    if (fullN) {
      int r = tid >> 3, cb = (tid & 7) * 8;
      size_t base = (size_t)r * LBUF + jb + cb;
      float4 v0 = *(float4*)&OutS[r][cb];
      float4 v1 = *(float4*)&OutS[r][cb + 4];
      *(float4*)&xout[base]     = v0;
      *(float4*)&xout[base + 4] = v1;
    } else {
      int c = tid & 63, r0 = tid >> 6;
      int j = jb + c;
      if (j < Tn)
#pragma unroll
        for (int rr = r0; rr < 32; rr += 4)
          xout[(size_t)rr * LBUF + j] = OutS[rr][c];
    }
  }
  if (fullN && ((off_s & 3) == 0) && jb >= off_s) {
    int r = tid >> 4, cb = (tid & 15) * 4;
    size_t base = (size_t)r * TF + (jb - off_s) + cb;
    float4 v = *(float4*)&OutS[32 + r][cb];
    if (first) {
      *(float4*)&skip[base] = v;
    } else {
      float4 o = *(const float4*)&skip[base];
      o.x += v.x; o.y += v.y; o.z += v.z; o.w += v.w;
      *(float4*)&skip[base] = o;
    }
  } else {
    int c = tid & 63, r0 = tid >> 6;
    int j = jb + c, js = j - off_s;
    if (j < Tn && js >= 0) {
#pragma unroll
      for (int rr = r0; rr < 16; rr += 4) {
        if (first) skip[(size_t)rr * TF + js]  = OutS[32 + rr][c];
        else       skip[(size_t)rr * TF + js] += OutS[32 + rr][c];
      }
    }
  }
}

// Fused final MLP. GEMM2 uses W2 hi only (error ~4e-3, analyzed safe).
// LDS 48KB -> 3 blocks/CU: w2s(16KB) aliases dead sks region; epilogue = 4 quarter passes.
__global__ __launch_bounds__(256) void k_final(
    const float* __restrict__ skip,
    const unsigned short* __restrict__ w1p,   // [256][32]
    const unsigned short* __restrict__ w2fp,  // [256][512] (hi 0..255 | lo 256..511)
    float* __restrict__ out)
{
  __shared__ alignas(16) char smem[49152];
  char* sks = smem;             // [64 col][128B hi|lo] ^((col&7)<<4), 8KB (pre-GEMM1)
  char* w2s = smem;             // [256 q][64B hi] ^((q&7)<<4), 16KB (aliases sks, post-GEMM1)
  char* h1s = smem + 16384;     // [64 col][512B hi] ^((col&31)<<4), 32KB
  float (*OutSq)[66] = (float (*)[66])&smem[0];  // [64][66] = 16896B, epilogue only

  int tid = threadIdx.x;
  int jb  = blockIdx.x * 64;
  int lane = tid & 63, w = tid >> 6;
  int lr = lane & 15, lg = lane >> 4;
  int col = w * 16 + lr;

  for (int i = tid; i < 1024; i += 256) {
    int c = i & 63, k2 = i >> 6;
    float v0 = (2 * k2 < 16)     ? fmaxf(skip[(size_t)(2 * k2) * TF + jb + c], 0.f) : 0.f;
    float v1 = (2 * k2 + 1 < 16) ? fmaxf(skip[(size_t)(2 * k2 + 1) * TF + jb + c], 0.f) : 0.f;
    unsigned short h0 = b16(v0), h1 = b16(v1);
    unsigned short l0 = b16(v0 - bf2f(h0)), l1 = b16(v1 - bf2f(h1));
    unsigned sw = (unsigned)(c & 7) << 4;
    *(unsigned*)(sks + ((c * 128 + k2 * 4) ^ sw))      = (unsigned)h0 | ((unsigned)h1 << 16);
    *(unsigned*)(sks + ((c * 128 + 64 + k2 * 4) ^ sw)) = (unsigned)l0 | ((unsigned)l1 << 16);
  }
  __syncthreads();

  unsigned swk = (unsigned)(col & 7) << 4;
  unsigned swh = (unsigned)(col & 31) << 4;

  // GEMM1 -> H1 (wave-local handoff, no barrier)
  {
    bf16x8 bh = *(const bf16x8*)(sks + ((col * 128 + lg * 16) ^ swk));
    bf16x8 bl = *(const bf16x8*)(sks + ((col * 128 + 64 + lg * 16) ^ swk));
#pragma unroll
    for (int mt = 0; mt < 16; ++mt) {
      bf16x8 ah = {0, 0, 0, 0, 0, 0, 0, 0};
      bf16x8 al = {0, 0, 0, 0, 0, 0, 0, 0};
      if (lg < 2) {
        int m = mt * 16 + lr;
        ah = *(const bf16x8*)(w1p + m * 32 + lg * 8);
        al = *(const bf16x8*)(w1p + m * 32 + 16 + lg * 8);
      }
      f32x4 z = {0.f, 0.f, 0.f, 0.f};
      z = __builtin_amdgcn_mfma_f32_16x16x32_bf16(ah, bh, z, 0, 0, 0);
      z = __builtin_amdgcn_mfma_f32_16x16x32_bf16(ah, bl, z, 0, 0, 0);
      z = __builtin_amdgcn_mfma_f32_16x16x32_bf16(al, bh, z, 0, 0, 0);
      int qb = (mt * 16 + lg * 4) * 2;
      unsigned p01 = (unsigned)b16(fmaxf(z[0], 0.f)) | ((unsigned)b16(fmaxf(z[1], 0.f)) << 16);
      unsigned p23 = (unsigned)b16(fmaxf(z[2], 0.f)) | ((unsigned)b16(fmaxf(z[3], 0.f)) << 16);
      *(unsigned*)(h1s + ((col * 512 + qb) ^ swh))     = p01;
      *(unsigned*)(h1s + ((col * 512 + qb + 4) ^ swh)) = p23;
    }
  }

  // GEMM2: K=256 in 8 chunks; W2 hi-only staged into w2s (16KB, aliases sks)
  f32x4 acco[16];
#pragma unroll
  for (int mt = 0; mt < 16; ++mt) acco[mt] = (f32x4){0.f, 0.f, 0.f, 0.f};

  for (int kb = 0; kb < 8; ++kb) {
    __syncthreads();   // kb=0: all GEMM1 sks reads done; else: prev w2s reads done
    for (int i = tid; i < 1024; i += 256) {
      int q = i >> 2, part = i & 3;
      uint4 v = *(const uint4*)(w2fp + q * 512 + kb * 32 + part * 8);
      *(uint4*)(w2s + ((q * 64 + part * 16) ^ ((q & 7) << 4))) = v;
    }
    __syncthreads();
    bf16x8 bh = *(const bf16x8*)(h1s + ((col * 512 + kb * 64 + lg * 16) ^ swh));
#pragma unroll
    for (int mt = 0; mt < 16; ++mt) {
      int row = mt * 16 + lr;
      bf16x8 ah = *(const bf16x8*)(w2s + ((row * 64 + lg * 16) ^ ((row & 7) << 4)));
      acco[mt] = __builtin_amdgcn_mfma_f32_16x16x32_bf16(ah, bh, acco[mt], 0, 0, 0);
    }
  }

  // epilogue: 4 quarter-q passes through OutSq (p fully unrolled -> acco static)
#pragma unroll
  for (int p = 0; p < 4; ++p) {
    __syncthreads();   // prev quarter reads (or last w2s/h1s reads) done
#pragma unroll
    for (int mq = 0; mq < 4; ++mq)
#pragma unroll
      for (int i = 0; i < 4; ++i)
        OutSq[mq * 16 + lg * 4 + i][col] = acco[p * 4 + mq][i];
    __syncthreads();
    int r = tid >> 2, cb = (tid & 3) * 16;
    size_t base = (size_t)(p * 64 + r) * TF + jb + cb;
#pragma unroll
    for (int v = 0; v < 4; ++v)
      *(float4*)&out[base + v * 4] = *(float4*)&OutSq[r][cb + v * 4];
  }
}

extern "C" void kernel_launch(void* const* d_in, const int* in_sizes, int n_in,
                              void* d_out, int out_size, void* d_ws, size_t ws_size,
                              hipStream_t stream) {
  const float* x_in     = (const float*)d_in[0];
  const float* w_init   = (const float*)d_in[1];
  const float* w_filter = (const float*)d_in[2];
  const float* w_gate   = (const float*)d_in[3];
  const float* w_res    = (const float*)d_in[4];
  const float* w_skip   = (const float*)d_in[5];
  const float* w_f1     = (const float*)d_in[6];
  const float* w_f2     = (const float*)d_in[7];
  float* out = (float*)d_out;

  float* xa    = (float*)d_ws;
  float* xb    = xa + 32 * (size_t)LBUF;
  float* skipb = xb + 32 * (size_t)LBUF;
  unsigned short* whp  = (unsigned short*)(skipb + 16 * (size_t)TF);
  unsigned short* w2p  = whp + 20 * 8192;
  unsigned short* w1p  = w2p + 20 * 3072;
  unsigned short* w2fp = w1p + 8192;

  k_pack<<<712, 256, 0, stream>>>(w_filter, w_gate, w_res, w_skip, w_f1, w_f2,
                                  whp, w2p, w1p, w2fp);

  int T = LBUF;
  for (int idx = 0; idx < 20; ++idx) {
    int d    = 1 << (idx % 10);
    int pad  = (d - (T % d)) % d;
    int Tn   = T + pad - d;
    int offs = Tn - TF;
    k_layer<<<(Tn + TB - 1) / TB, 256, 0, stream>>>(
        xa, xb, skipb,
        (const unsigned*)(whp + (size_t)idx * 8192), w2p + (size_t)idx * 3072,
        (idx == 0) ? x_in : nullptr, w_init,
        Tn, T, d, pad, offs, (idx == 0) ? 1 : 0, (idx == 19) ? 0 : 1);
    float* t = xa; xa = xb; xb = t;
    T = Tn;
  }

  k_final<<<TF / 64, 256, 0, stream>>>(skipb, w1p, w2fp, out);
}

// Round 16
// 588.345 us; speedup vs baseline: 1.3664x; 1.0280x over previous
//
#include <hip/hip_runtime.h>
#include <hip/hip_bf16.h>

#define LBUF 131072
#define TF   130048
#define TB   64

typedef short bf16x8 __attribute__((ext_vector_type(8)));
typedef float f32x4  __attribute__((ext_vector_type(4)));

__device__ __forceinline__ float ftanh(float x) {
  float ax = fminf(fabsf(x), 15.0f);
  float t  = __expf(2.0f * ax);
  float r  = 1.0f - 2.0f / (t + 1.0f);
  return copysignf(r, x);
}
__device__ __forceinline__ unsigned short b16(float f) {
  return __builtin_bit_cast(unsigned short, __float2bfloat16(f));
}
__device__ __forceinline__ float bf2f(unsigned short h) {
  return __builtin_bit_cast(float, ((unsigned)h) << 16);
}

// Pre-pack all weights into split hi/lo bf16 planes (once per call).
// Conv planes use k' = tap*32 + c (left half k'<32, right half k'>=32).
__global__ __launch_bounds__(256) void k_pack(
    const float* __restrict__ wf, const float* __restrict__ wg,
    const float* __restrict__ wr, const float* __restrict__ wsk,
    const float* __restrict__ w1, const float* __restrict__ w2,
    unsigned short* __restrict__ whp, unsigned short* __restrict__ w2p,
    unsigned short* __restrict__ w1p, unsigned short* __restrict__ w2fp)
{
  int i = blockIdx.x * 256 + threadIdx.x;
  if (i < 81920) {                       // conv weights: 20 x 4096
    int l = i >> 12, r = i & 4095;
    int m = r >> 6, k = r & 63;
    int c = k & 31, tap = k >> 5;
    float v = (m < 32) ? wf[l * 2048 + m * 64 + c * 2 + tap]
                       : wg[l * 2048 + (m - 32) * 64 + c * 2 + tap];
    unsigned short h = b16(v);
    whp[l * 8192 + m * 128 + k]      = h;
    whp[l * 8192 + m * 128 + 64 + k] = b16(v - bf2f(h));
  } else if (i < 112640) {               // 1x1 weights: 20 x 1536
    int t = i - 81920;
    int l = t / 1536, r = t - l * 1536;
    int m = r >> 5, o = r & 31;
    float v = (m < 32) ? wr[l * 1024 + m * 32 + o] : wsk[l * 512 + (m - 32) * 32 + o];
    unsigned short h = b16(v);
    w2p[l * 3072 + m * 64 + o]      = h;
    w2p[l * 3072 + m * 64 + 32 + o] = b16(v - bf2f(h));
  } else if (i < 116736) {               // W1: 4096
    int t = i - 112640;
    int q = t >> 4, k = t & 15;
    float v = w1[q * 16 + k];
    unsigned short h = b16(v);
    w1p[q * 32 + k]      = h;
    w1p[q * 32 + 16 + k] = b16(v - bf2f(h));
  } else {                               // W2: 65536
    int t = i - 116736;
    int q = t >> 8, k = t & 255;
    float v = w2[q * 256 + k];
    unsigned short h = b16(v);
    w2fp[q * 512 + k]       = h;
    w2fp[q * 512 + 256 + k] = b16(v - bf2f(h));
  }
}

// Fused 6 small-d layers (d = 1,2,4,8,16,32) in final-time coords:
// layer L taps at f-d and f; skip of all 6 layers lands at the same f.
// Block owns final cols f in [F, F+64); halo 64 on the left; X updated in LDS.
__global__ __launch_bounds__(256) void k_fuse6(
    const float* __restrict__ xin, float* __restrict__ xout,
    float* __restrict__ skip,
    const unsigned short* __restrict__ whp6,   // 6 planes, stride 8192
    const unsigned short* __restrict__ w2p6,   // 6 planes, stride 3072
    const float* __restrict__ rawin, const float* __restrict__ w_init,
    int O_in, int O_out, int nextra, int first)
{
  __shared__ alignas(16) char xs[32768];  // [128 col][256B: Lhi 64|Rhi 64|Llo 64|Rlo 64] ^((col&15)<<4)
  __shared__ alignas(16) char gs[16384];  // [128 col][128B: hi|lo] ^((col&7)<<4)
  __shared__ alignas(16) char wb[16384];  // [64 m][256B hi|lo] ^((m&15)<<4); aliased OutS at end
  float (*OutS)[68] = (float (*)[68])wb;  // [48][68] f32

  int tid = threadIdx.x, lane = tid & 63, w = tid >> 6;
  int lr = lane & 15, lg = lane >> 4;
  int F = ((int)blockIdx.x - nextra) * 64;

  // ---- stage X (layer-0 input, d0=1: left=f-1, right=f) ----
  for (int i = tid; i < 4096; i += 256) {
    int col = i & 127, c = i >> 7;
    int j1 = F - 64 + col + O_in, j0 = j1 - 1;
    float v0, v1;
    if (rawin) {
      float s = w_init[c];
      v0 = (j0 >= 0) ? s * rawin[j0] : 0.f;
      v1 = (j1 >= 0) ? s * rawin[j1] : 0.f;
    } else {
      v0 = (j0 >= 0) ? xin[(size_t)c * LBUF + j0] : 0.f;
      v1 = (j1 >= 0) ? xin[(size_t)c * LBUF + j1] : 0.f;
    }
    unsigned short h0 = b16(v0), l0 = b16(v0 - bf2f(h0));
    unsigned short h1 = b16(v1), l1 = b16(v1 - bf2f(h1));
    unsigned sw = (unsigned)(col & 15) << 4;
    *(unsigned short*)(xs + ((col * 256 +       c * 2) ^ sw)) = h0;
    *(unsigned short*)(xs + ((col * 256 +  64 + c * 2) ^ sw)) = h1;
    *(unsigned short*)(xs + ((col * 256 + 128 + c * 2) ^ sw)) = l0;
    *(unsigned short*)(xs + ((col * 256 + 192 + c * 2) ^ sw)) = l1;
  }
  // ---- stage W layer 0 ----
  for (int i = tid; i < 4096; i += 256) {
    int m = i >> 6, j = i & 63;
    *(unsigned*)(wb + ((m * 256 + j * 4) ^ ((m & 15) << 4))) = ((const unsigned*)whp6)[i];
  }
  __syncthreads();

  float skacc[4] = {0.f, 0.f, 0.f, 0.f};
  const int colv[2] = {w * 16 + lr, 64 + w * 16 + lr};
  unsigned swx = (unsigned)lr << 4;                 // (col&15)<<4, same for both cols
  unsigned swg = (unsigned)(colv[0] & 7) << 4;      // same for both cols

#pragma unroll
  for (int L = 0; L < 6; ++L) {
    constexpr int DN[5] = {2, 4, 8, 16, 32};        // d of layer L+1

    // 1x1 fragments (per layer, per-lane from packed global; L2-hot)
    const unsigned short* w2pl = w2p6 + L * 3072;
    bf16x8 a2h[3], a2l[3];
#pragma unroll
    for (int mt = 0; mt < 3; ++mt) {
      int m = mt * 16 + lr;
      a2h[mt] = *(const bf16x8*)(w2pl + m * 64 + lg * 8);
      a2l[mt] = *(const bf16x8*)(w2pl + m * 64 + 32 + lg * 8);
    }

    // ---- GEMM1: K=64, 3-term split, 2 col-tiles ----
    f32x4 acc1[2][4];
#pragma unroll
    for (int n = 0; n < 2; ++n)
#pragma unroll
      for (int mt = 0; mt < 4; ++mt) acc1[n][mt] = (f32x4){0.f, 0.f, 0.f, 0.f};
#pragma unroll
    for (int ks = 0; ks < 2; ++ks) {
      bf16x8 bh[2], bl[2];
#pragma unroll
      for (int n = 0; n < 2; ++n) {
        bh[n] = *(const bf16x8*)(xs + ((colv[n] * 256 + ks * 64 + lg * 16) ^ swx));
        bl[n] = *(const bf16x8*)(xs + ((colv[n] * 256 + 128 + ks * 64 + lg * 16) ^ swx));
      }
#pragma unroll
      for (int mt = 0; mt < 4; ++mt) {
        bf16x8 ah = *(const bf16x8*)(wb + (((mt * 16 + lr) * 256 + ks * 64 + lg * 16) ^ swx));
        bf16x8 al = *(const bf16x8*)(wb + (((mt * 16 + lr) * 256 + 128 + ks * 64 + lg * 16) ^ swx));
#pragma unroll
        for (int n = 0; n < 2; ++n) {
          acc1[n][mt] = __builtin_amdgcn_mfma_f32_16x16x32_bf16(ah, bh[n], acc1[n][mt], 0, 0, 0);
          acc1[n][mt] = __builtin_amdgcn_mfma_f32_16x16x32_bf16(ah, bl[n], acc1[n][mt], 0, 0, 0);
          acc1[n][mt] = __builtin_amdgcn_mfma_f32_16x16x32_bf16(al, bh[n], acc1[n][mt], 0, 0, 0);
        }
      }
    }

    // ---- gate -> gs (wave-local) ----
#pragma unroll
    for (int n = 0; n < 2; ++n) {
      int col = colv[n];
#pragma unroll
      for (int t = 0; t < 2; ++t) {
        float g0 = ftanh(acc1[n][t][0]) * ftanh(acc1[n][t + 2][0]);
        float g1 = ftanh(acc1[n][t][1]) * ftanh(acc1[n][t + 2][1]);
        float g2 = ftanh(acc1[n][t][2]) * ftanh(acc1[n][t + 2][2]);
        float g3 = ftanh(acc1[n][t][3]) * ftanh(acc1[n][t + 2][3]);
        unsigned short h0 = b16(g0), h1 = b16(g1), h2 = b16(g2), h3 = b16(g3);
        unsigned short l0 = b16(g0 - bf2f(h0)), l1 = b16(g1 - bf2f(h1));
        unsigned short l2 = b16(g2 - bf2f(h2)), l3 = b16(g3 - bf2f(h3));
        int ob = (t * 16 + lg * 4) * 2;
        *(unsigned*)(gs + ((col * 128 + ob) ^ swg))          = (unsigned)h0 | ((unsigned)h1 << 16);
        *(unsigned*)(gs + ((col * 128 + ob + 4) ^ swg))      = (unsigned)h2 | ((unsigned)h3 << 16);
        *(unsigned*)(gs + ((col * 128 + 64 + ob) ^ swg))     = (unsigned)l0 | ((unsigned)l1 << 16);
        *(unsigned*)(gs + ((col * 128 + 64 + ob + 4) ^ swg)) = (unsigned)l2 | ((unsigned)l3 << 16);
      }
    }

    // ---- GEMM2: K=32, 3-term, A regs; wave-local B ----
    f32x4 acc2[2][3];
#pragma unroll
    for (int n = 0; n < 2; ++n) {
      bf16x8 bgh = *(const bf16x8*)(gs + ((colv[n] * 128 + lg * 16) ^ swg));
      bf16x8 bgl = *(const bf16x8*)(gs + ((colv[n] * 128 + 64 + lg * 16) ^ swg));
#pragma unroll
      for (int mt = 0; mt < 3; ++mt) {
        f32x4 z = {0.f, 0.f, 0.f, 0.f};
        z = __builtin_amdgcn_mfma_f32_16x16x32_bf16(a2h[mt], bgh, z, 0, 0, 0);
        z = __builtin_amdgcn_mfma_f32_16x16x32_bf16(a2h[mt], bgl, z, 0, 0, 0);
        acc2[n][mt] = __builtin_amdgcn_mfma_f32_16x16x32_bf16(a2l[mt], bgh, z, 0, 0, 0);
      }
    }
#pragma unroll
    for (int i = 0; i < 4; ++i) skacc[i] += acc2[1][2][i];

    // ---- residual (right-tap values, from xs right halves) ----
    float res[2][2][4];
#pragma unroll
    for (int n = 0; n < 2; ++n)
#pragma unroll
      for (int mt = 0; mt < 2; ++mt) {
        int m0b = (mt * 16 + lg * 4) * 2;
        unsigned hA = *(const unsigned*)(xs + ((colv[n] * 256 + 64 + m0b) ^ swx));
        unsigned hB = *(const unsigned*)(xs + ((colv[n] * 256 + 64 + m0b + 4) ^ swx));
        unsigned lA = *(const unsigned*)(xs + ((colv[n] * 256 + 192 + m0b) ^ swx));
        unsigned lB = *(const unsigned*)(xs + ((colv[n] * 256 + 192 + m0b + 4) ^ swx));
        res[n][mt][0] = bf2f((unsigned short)(hA & 0xffffu)) + bf2f((unsigned short)(lA & 0xffffu));
        res[n][mt][1] = bf2f((unsigned short)(hA >> 16))     + bf2f((unsigned short)(lA >> 16));
        res[n][mt][2] = bf2f((unsigned short)(hB & 0xffffu)) + bf2f((unsigned short)(lB & 0xffffu));
        res[n][mt][3] = bf2f((unsigned short)(hB >> 16))     + bf2f((unsigned short)(lB >> 16));
      }
    __syncthreads();   // all xs/wb reads of this layer done

    if (L < 5) {
      // stage next layer's conv weights (wb free)
      for (int i = tid; i < 4096; i += 256) {
        int m = i >> 6, j = i & 63;
        *(unsigned*)(wb + ((m * 256 + j * 4) ^ ((m & 15) << 4))) =
            ((const unsigned*)(whp6 + (L + 1) * 8192))[i];
      }
      // xs in-place update: new x -> own col right half, col+dn left half
      int dn = DN[L];
#pragma unroll
      for (int n = 0; n < 2; ++n) {
        int col = colv[n];
#pragma unroll
        for (int mt = 0; mt < 2; ++mt) {
          int m0b = (mt * 16 + lg * 4) * 2;
          float v0 = acc2[n][mt][0] + res[n][mt][0];
          float v1 = acc2[n][mt][1] + res[n][mt][1];
          float v2 = acc2[n][mt][2] + res[n][mt][2];
          float v3 = acc2[n][mt][3] + res[n][mt][3];
          unsigned short h0 = b16(v0), h1 = b16(v1), h2 = b16(v2), h3 = b16(v3);
          unsigned short l0 = b16(v0 - bf2f(h0)), l1 = b16(v1 - bf2f(h1));
          unsigned short l2 = b16(v2 - bf2f(h2)), l3 = b16(v3 - bf2f(h3));
          unsigned HA = (unsigned)h0 | ((unsigned)h1 << 16);
          unsigned HB = (unsigned)h2 | ((unsigned)h3 << 16);
          unsigned LA = (unsigned)l0 | ((unsigned)l1 << 16);
          unsigned LB = (unsigned)l2 | ((unsigned)l3 << 16);
          *(unsigned*)(xs + ((col * 256 + 64 + m0b) ^ swx))      = HA;
          *(unsigned*)(xs + ((col * 256 + 64 + m0b + 4) ^ swx))  = HB;
          *(unsigned*)(xs + ((col * 256 + 192 + m0b) ^ swx))     = LA;
          *(unsigned*)(xs + ((col * 256 + 192 + m0b + 4) ^ swx)) = LB;
          int cd = col + dn;
          if (cd < 128) {
            unsigned sw2 = (unsigned)(cd & 15) << 4;
            *(unsigned*)(xs + ((cd * 256 + m0b) ^ sw2))       = HA;
            *(unsigned*)(xs + ((cd * 256 + m0b + 4) ^ sw2))   = HB;
            *(unsigned*)(xs + ((cd * 256 + 128 + m0b) ^ sw2)) = LA;
            *(unsigned*)(xs + ((cd * 256 + 128 + m0b + 4) ^ sw2)) = LB;
          }
        }
      }
      __syncthreads();
    } else {
      // ---- epilogue (L == 5): OutS aliases wb (reads done) ----
      int oc = colv[1] - 64;
#pragma unroll
      for (int mt = 0; mt < 2; ++mt)
#pragma unroll
        for (int i = 0; i < 4; ++i)
          OutS[mt * 16 + lg * 4 + i][oc] = acc2[1][mt][i] + res[1][mt][i];
#pragma unroll
      for (int i = 0; i < 4; ++i)
        OutS[32 + lg * 4 + i][oc] = skacc[i];
      __syncthreads();

      int jb0 = F + O_out;
      if (jb0 >= 0) {
        int r = tid >> 3, cb = (tid & 7) * 8;
        size_t base = (size_t)r * LBUF + jb0 + cb;
        *(float4*)&xout[base]     = *(float4*)&OutS[r][cb];
        *(float4*)&xout[base + 4] = *(float4*)&OutS[r][cb + 4];
      } else {
        int c = tid & 63, r0 = tid >> 6;
        int j = jb0 + c;
        if (j >= 0)
#pragma unroll
          for (int rr = r0; rr < 32; rr += 4)
            xout[(size_t)rr * LBUF + j] = OutS[rr][c];
      }
      if (F >= 0) {
        int r = tid >> 4, cb = (tid & 15) * 4;
        size_t base = (size_t)r * TF + F + cb;
        float4 v = *(float4*)&OutS[32 + r][cb];
        if (first) {
          *(float4*)&skip[base] = v;
        } else {
          float4 o = *(const float4*)&skip[base];
          o.x += v.x; o.y += v.y; o.z += v.z; o.w += v.w;
          *(float4*)&skip[base] = o;
        }
      }
    }
  }
}

// One unfused dilated layer (round-12 structure, new k' = tap*32+c packing).
__global__ __launch_bounds__(256) void k_layer(
    const float* __restrict__ xin, float* __restrict__ xout,
    float* __restrict__ skip,
    const unsigned* __restrict__ wsrc,        // packed conv w, 4096 u32
    const unsigned short* __restrict__ w2p,   // packed 1x1, [48][64]
    int Tn, int Told, int d, int pad, int off_s, int writex)
{
  __shared__ alignas(16) char xs[16384];   // [64 col][256B] ^((col&15)<<4)
  __shared__ alignas(16) char gs[8192];    // [64 col][128B] ^((col&7)<<4)
  __shared__ alignas(16) char wbuf[16384]; // [64 m][256B] ^((m&15)<<4); later OutS
  float (*OutS)[68] = (float (*)[68])&wbuf[0];

  int tid = threadIdx.x;
  int jb  = blockIdx.x * TB;
  int lane = tid & 63, w = tid >> 6;
  int lr = lane & 15, lg = lane >> 4;

  bf16x8 a2h[3], a2l[3];
#pragma unroll
  for (int mt = 0; mt < 3; ++mt) {
    int m = mt * 16 + lr;
    a2h[mt] = *(const bf16x8*)(w2p + m * 64 + lg * 8);
    a2l[mt] = *(const bf16x8*)(w2p + m * 64 + 32 + lg * 8);
  }

  for (int i = tid; i < 4096; i += 256) {
    int m = i >> 6, j = i & 63;
    *(unsigned*)(wbuf + ((m * 256 + j * 4) ^ ((m & 15) << 4))) = wsrc[i];
  }
  for (int i = tid; i < 2048; i += 256) {
    int col = i & 63, c = i >> 6;
    int e0 = jb + col - pad, e1 = e0 + d;
    float v0 = (e0 >= 0 && e0 < Told) ? xin[(size_t)c * LBUF + e0] : 0.f;
    float v1 = (e1 < Told) ? xin[(size_t)c * LBUF + e1] : 0.f;
    unsigned short h0 = b16(v0), l0 = b16(v0 - bf2f(h0));
    unsigned short h1 = b16(v1), l1 = b16(v1 - bf2f(h1));
    unsigned sw = (unsigned)(col & 15) << 4;
    *(unsigned short*)(xs + ((col * 256 +       c * 2) ^ sw)) = h0;
    *(unsigned short*)(xs + ((col * 256 +  64 + c * 2) ^ sw)) = h1;
    *(unsigned short*)(xs + ((col * 256 + 128 + c * 2) ^ sw)) = l0;
    *(unsigned short*)(xs + ((col * 256 + 192 + c * 2) ^ sw)) = l1;
  }
  __syncthreads();

  int col = w * 16 + lr;
  unsigned swx = (unsigned)lr << 4;

  f32x4 acc1[4];
#pragma unroll
  for (int mt = 0; mt < 4; ++mt) acc1[mt] = (f32x4){0.f, 0.f, 0.f, 0.f};
#pragma unroll
  for (int ks = 0; ks < 2; ++ks) {
    bf16x8 bh = *(const bf16x8*)(xs + ((col * 256 + ks * 64 + lg * 16) ^ swx));
    bf16x8 bl = *(const bf16x8*)(xs + ((col * 256 + 128 + ks * 64 + lg * 16) ^ swx));
#pragma unroll
    for (int mt = 0; mt < 4; ++mt) {
      int row = mt * 16 + lr;
      bf16x8 ah = *(const bf16x8*)(wbuf + ((row * 256 + ks * 64 + lg * 16) ^ swx));
      bf16x8 al = *(const bf16x8*)(wbuf + ((row * 256 + 128 + ks * 64 + lg * 16) ^ swx));
      acc1[mt] = __builtin_amdgcn_mfma_f32_16x16x32_bf16(ah, bh, acc1[mt], 0, 0, 0);
      acc1[mt] = __builtin_amdgcn_mfma_f32_16x16x32_bf16(ah, bl, acc1[mt], 0, 0, 0);
      acc1[mt] = __builtin_amdgcn_mfma_f32_16x16x32_bf16(al, bh, acc1[mt], 0, 0, 0);
    }
  }

  unsigned swg = (unsigned)(col & 7) << 4;
#pragma unroll
  for (int t = 0; t < 2; ++t) {
    float g0 = ftanh(acc1[t][0]) * ftanh(acc1[t + 2][0]);
    float g1 = ftanh(acc1[t][1]) * ftanh(acc1[t + 2][1]);
    float g2 = ftanh(acc1[t][2]) * ftanh(acc1[t + 2][2]);
    float g3 = ftanh(acc1[t][3]) * ftanh(acc1[t + 2][3]);
    unsigned short h0 = b16(g0), h1 = b16(g1), h2 = b16(g2), h3 = b16(g3);
    unsigned short l0 = b16(g0 - bf2f(h0)), l1 = b16(g1 - bf2f(h1));
    unsigned short l2 = b16(g2 - bf2f(h2)), l3 = b16(g3 - bf2f(h3));
    int ob = (t * 16 + lg * 4) * 2;
    *(unsigned*)(gs + ((col * 128 + ob) ^ swg))          = (unsigned)h0 | ((unsigned)h1 << 16);
    *(unsigned*)(gs + ((col * 128 + ob + 4) ^ swg))      = (unsigned)h2 | ((unsigned)h3 << 16);
    *(unsigned*)(gs + ((col * 128 + 64 + ob) ^ swg))     = (unsigned)l0 | ((unsigned)l1 << 16);
    *(unsigned*)(gs + ((col * 128 + 64 + ob + 4) ^ swg)) = (unsigned)l2 | ((unsigned)l3 << 16);
  }

  f32x4 acc2[3];
  {
    bf16x8 bgh = *(const bf16x8*)(gs + ((col * 128 + lg * 16) ^ swg));
    bf16x8 bgl = *(const bf16x8*)(gs + ((col * 128 + 64 + lg * 16) ^ swg));
#pragma unroll
    for (int mt = 0; mt < 3; ++mt) {
      f32x4 z = {0.f, 0.f, 0.f, 0.f};
      z = __builtin_amdgcn_mfma_f32_16x16x32_bf16(a2h[mt], bgh, z, 0, 0, 0);
      z = __builtin_amdgcn_mfma_f32_16x16x32_bf16(a2h[mt], bgl, z, 0, 0, 0);
      acc2[mt] = __builtin_amdgcn_mfma_f32_16x16x32_bf16(a2l[mt], bgh, z, 0, 0, 0);
    }
  }

  __syncthreads();
  {
#pragma unroll
    for (int mt = 0; mt < 2; ++mt)
#pragma unroll
      for (int i = 0; i < 4; ++i) {
        int m = mt * 16 + lg * 4 + i;
        unsigned short xh = *(unsigned short*)(xs + ((col * 256 + 64 + m * 2) ^ swx));
        unsigned short xl = *(unsigned short*)(xs + ((col * 256 + 192 + m * 2) ^ swx));
        OutS[m][col] = acc2[mt][i] + (bf2f(xh) + bf2f(xl));
      }
#pragma unroll
    for (int i = 0; i < 4; ++i)
      OutS[32 + lg * 4 + i][col] = acc2[2][i];
  }
  __syncthreads();

  bool fullN = (jb + TB <= Tn);
  if (writex) {
    if (fullN) {
      int r = tid >> 3, cb = (tid & 7) * 8;
      size_t base = (size_t)r * LBUF + jb + cb;
      *(float4*)&xout[base]     = *(float4*)&OutS[r][cb];
      *(float4*)&xout[base + 4] = *(float4*)&OutS[r][cb + 4];
    } else {
      int c = tid & 63, r0 = tid >> 6;
      int j = jb + c;
      if (j < Tn)
#pragma unroll
        for (int rr = r0; rr < 32; rr += 4)
          xout[(size_t)rr * LBUF + j] = OutS[rr][c];
    }
  }
  if (fullN && ((off_s & 3) == 0) && jb >= off_s) {
    int r = tid >> 4, cb = (tid & 15) * 4;
    size_t base = (size_t)r * TF + (jb - off_s) + cb;
    float4 v = *(float4*)&OutS[32 + r][cb];
    float4 o = *(const float4*)&skip[base];
    o.x += v.x; o.y += v.y; o.z += v.z; o.w += v.w;
    *(float4*)&skip[base] = o;
  } else {
    int c = tid & 63, r0 = tid >> 6;
    int j = jb + c, js = j - off_s;
    if (j < Tn && js >= 0) {
#pragma unroll
      for (int rr = r0; rr < 16; rr += 4)
        skip[(size_t)rr * TF + js] += OutS[32 + rr][c];
    }
  }
}

// Fused final MLP (round-15 version, unchanged).
__global__ __launch_bounds__(256) void k_final(
    const float* __restrict__ skip,
    const unsigned short* __restrict__ w1p,
    const unsigned short* __restrict__ w2fp,
    float* __restrict__ out)
{
  __shared__ alignas(16) char smem[49152];
  char* sks = smem;
  char* w2s = smem;
  char* h1s = smem + 16384;
  float (*OutSq)[66] = (float (*)[66])&smem[0];

  int tid = threadIdx.x;
  int jb  = blockIdx.x * 64;
  int lane = tid & 63, w = tid >> 6;
  int lr = lane & 15, lg = lane >> 4;
  int col = w * 16 + lr;

  for (int i = tid; i < 1024; i += 256) {
    int c = i & 63, k2 = i >> 6;
    float v0 = (2 * k2 < 16)     ? fmaxf(skip[(size_t)(2 * k2) * TF + jb + c], 0.f) : 0.f;
    float v1 = (2 * k2 + 1 < 16) ? fmaxf(skip[(size_t)(2 * k2 + 1) * TF + jb + c], 0.f) : 0.f;
    unsigned short h0 = b16(v0), h1 = b16(v1);
    unsigned short l0 = b16(v0 - bf2f(h0)), l1 = b16(v1 - bf2f(h1));
    unsigned sw = (unsigned)(c & 7) << 4;
    *(unsigned*)(sks + ((c * 128 + k2 * 4) ^ sw))      = (unsigned)h0 | ((unsigned)h1 << 16);
    *(unsigned*)(sks + ((c * 128 + 64 + k2 * 4) ^ sw)) = (unsigned)l0 | ((unsigned)l1 << 16);
  }
  __syncthreads();

  unsigned swk = (unsigned)(col & 7) << 4;
  unsigned swh = (unsigned)(col & 31) << 4;

  {
    bf16x8 bh = *(const bf16x8*)(sks + ((col * 128 + lg * 16) ^ swk));
    bf16x8 bl = *(const bf16x8*)(sks + ((col * 128 + 64 + lg * 16) ^ swk));
#pragma unroll
    for (int mt = 0; mt < 16; ++mt) {
      bf16x8 ah = {0, 0, 0, 0, 0, 0, 0, 0};
      bf16x8 al = {0, 0, 0, 0, 0, 0, 0, 0};
      if (lg < 2) {
        int m = mt * 16 + lr;
        ah = *(const bf16x8*)(w1p + m * 32 + lg * 8);
        al = *(const bf16x8*)(w1p + m * 32 + 16 + lg * 8);
      }
      f32x4 z = {0.f, 0.f, 0.f, 0.f};
      z = __builtin_amdgcn_mfma_f32_16x16x32_bf16(ah, bh, z, 0, 0, 0);
      z = __builtin_amdgcn_mfma_f32_16x16x32_bf16(ah, bl, z, 0, 0, 0);
      z = __builtin_amdgcn_mfma_f32_16x16x32_bf16(al, bh, z, 0, 0, 0);
      int qb = (mt * 16 + lg * 4) * 2;
      unsigned p01 = (unsigned)b16(fmaxf(z[0], 0.f)) | ((unsigned)b16(fmaxf(z[1], 0.f)) << 16);
      unsigned p23 = (unsigned)b16(fmaxf(z[2], 0.f)) | ((unsigned)b16(fmaxf(z[3], 0.f)) << 16);
      *(unsigned*)(h1s + ((col * 512 + qb) ^ swh))     = p01;
      *(unsigned*)(h1s + ((col * 512 + qb + 4) ^ swh)) = p23;
    }
  }

  f32x4 acco[16];
#pragma unroll
  for (int mt = 0; mt < 16; ++mt) acco[mt] = (f32x4){0.f, 0.f, 0.f, 0.f};

  for (int kb = 0; kb < 8; ++kb) {
    __syncthreads();
    for (int i = tid; i < 1024; i += 256) {
      int q = i >> 2, part = i & 3;
      uint4 v = *(const uint4*)(w2fp + q * 512 + kb * 32 + part * 8);
      *(uint4*)(w2s + ((q * 64 + part * 16) ^ ((q & 7) << 4))) = v;
    }
    __syncthreads();
    bf16x8 bh = *(const bf16x8*)(h1s + ((col * 512 + kb * 64 + lg * 16) ^ swh));
#pragma unroll
    for (int mt = 0; mt < 16; ++mt) {
      int row = mt * 16 + lr;
      bf16x8 ah = *(const bf16x8*)(w2s + ((row * 64 + lg * 16) ^ ((row & 7) << 4)));
      acco[mt] = __builtin_amdgcn_mfma_f32_16x16x32_bf16(ah, bh, acco[mt], 0, 0, 0);
    }
  }

#pragma unroll
  for (int p = 0; p < 4; ++p) {
    __syncthreads();
#pragma unroll
    for (int mq = 0; mq < 4; ++mq)
#pragma unroll
      for (int i = 0; i < 4; ++i)
        OutSq[mq * 16 + lg * 4 + i][col] = acco[p * 4 + mq][i];
    __syncthreads();
    int r = tid >> 2, cb = (tid & 3) * 16;
    size_t base = (size_t)(p * 64 + r) * TF + jb + cb;
#pragma unroll
    for (int v = 0; v < 4; ++v)
      *(float4*)&out[base + v * 4] = *(float4*)&OutSq[r][cb + v * 4];
  }
}

extern "C" void kernel_launch(void* const* d_in, const int* in_sizes, int n_in,
                              void* d_out, int out_size, void* d_ws, size_t ws_size,
                              hipStream_t stream) {
  const float* x_in     = (const float*)d_in[0];
  const float* w_init   = (const float*)d_in[1];
  const float* w_filter = (const float*)d_in[2];
  const float* w_gate   = (const float*)d_in[3];
  const float* w_res    = (const float*)d_in[4];
  const float* w_skip   = (const float*)d_in[5];
  const float* w_f1     = (const float*)d_in[6];
  const float* w_f2     = (const float*)d_in[7];
  float* out = (float*)d_out;

  float* xa    = (float*)d_ws;
  float* xb    = xa + 32 * (size_t)LBUF;
  float* skipb = xb + 32 * (size_t)LBUF;
  unsigned short* whp  = (unsigned short*)(skipb + 16 * (size_t)TF);
  unsigned short* w2p  = whp + 20 * 8192;
  unsigned short* w1p  = w2p + 20 * 3072;
  unsigned short* w2fp = w1p + 8192;

  k_pack<<<712, 256, 0, stream>>>(w_filter, w_gate, w_res, w_skip, w_f1, w_f2,
                                  whp, w2p, w1p, w2fp);

  // Decade 1: layers 0-5 fused (input = raw x, init conv folded). Output x5 -> xa.
  k_fuse6<<<2048, 256, 0, stream>>>(xb, xa, skipb, whp, w2p, x_in, w_init,
                                    1024, 992, 16, 1);
  // Layers 6-9 (d = 64..512), hardcoded dims.
  k_layer<<<(131008 + 63) / 64, 256, 0, stream>>>(xa, xb, skipb,
      (const unsigned*)(whp + 6 * 8192), w2p + 6 * 3072, 131008, 131040, 64, 32, 960, 1);
  k_layer<<<(130944 + 63) / 64, 256, 0, stream>>>(xb, xa, skipb,
      (const unsigned*)(whp + 7 * 8192), w2p + 7 * 3072, 130944, 131008, 128, 64, 896, 1);
  k_layer<<<(130816 + 63) / 64, 256, 0, stream>>>(xa, xb, skipb,
      (const unsigned*)(whp + 8 * 8192), w2p + 8 * 3072, 130816, 130944, 256, 128, 768, 1);
  k_layer<<<(130560 + 63) / 64, 256, 0, stream>>>(xb, xa, skipb,
      (const unsigned*)(whp + 9 * 8192), w2p + 9 * 3072, 130560, 130816, 512, 256, 512, 1);
  // Decade 2: layers 10-15 fused. Input x9 (xa, O_in=512) -> x15 (xb, O_out=480).
  k_fuse6<<<2040, 256, 0, stream>>>(xa, xb, skipb, whp + 10 * 8192, w2p + 10 * 3072,
                                    nullptr, w_init, 512, 480, 8, 0);
  // Layers 16-19.
  k_layer<<<(130496 + 63) / 64, 256, 0, stream>>>(xb, xa, skipb,
      (const unsigned*)(whp + 16 * 8192), w2p + 16 * 3072, 130496, 130528, 64, 32, 448, 1);
  k_layer<<<(130432 + 63) / 64, 256, 0, stream>>>(xa, xb, skipb,
      (const unsigned*)(whp + 17 * 8192), w2p + 17 * 3072, 130432, 130496, 128, 64, 384, 1);
  k_layer<<<(130304 + 63) / 64, 256, 0, stream>>>(xb, xa, skipb,
      (const unsigned*)(whp + 18 * 8192), w2p + 18 * 3072, 130304, 130432, 256, 128, 256, 1);
  k_layer<<<(130048 + 63) / 64, 256, 0, stream>>>(xa, xb, skipb,
      (const unsigned*)(whp + 19 * 8192), w2p + 19 * 3072, 130048, 130304, 512, 256, 0, 0);

  k_final<<<TF / 64, 256, 0, stream>>>(skipb, w1p, w2fp, out);
}